// Round 6
// baseline (15131.131 us; speedup 1.0000x reference)
//
#include <hip/hip_runtime.h>
#include <cstdint>
#include <cstddef>

#define Bsz 32
#define Tn  2048
#define Dn  64
#define Hn  512
#define Cn  10
#define NG  16   // blocks per batch-group (sync domain)
#define UG  32   // units per block
#define NBG 8    // batch groups
#define BPG 4    // batches per group
#define KS  32   // K-split lanes per unit
#define NTH 1024 // 32 units x 32 ks
#define XW  2048 // ring words per (parity,bg) = 512 units x 4 batches

__device__ __forceinline__ float sigmoidf_(float v) { return 1.f / (1.f + __expf(-v)); }
__device__ __forceinline__ float tanhf_(float v) {
  const float c = fminf(fmaxf(v, -15.f), 15.f);
  const float e = __expf(-2.f * c);
  return (1.f - e) / (1.f + e);
}

// hT layout: h[k][b] skewed: off(k,b) = k*4 + ((k>>4)<<2) + b.
// ring word j = g*128 + u*4 + b  (unit = g*32+u)  ->  off = j + 4*(j>>6).

__global__ __launch_bounds__(NTH) void gru_main(
    const float* __restrict__ x, const float* __restrict__ w_ih,
    const float* __restrict__ w_hh, const float* __restrict__ b_ih,
    const float* __restrict__ b_hh, float* __restrict__ hs,
    unsigned long long* __restrict__ xch)   // [2][NBG][XW] tagged ring
{
  const int g   = blockIdx.x >> 3;          // 0..15
  const int bg  = blockIdx.x & (NBG - 1);   // 0..7
  const int tid = threadIdx.x;
  const int ks  = tid & (KS - 1);
  const int u   = tid >> 5;                 // unit within block 0..31

  __shared__ float hTb[2][2176];
  __shared__ float xT[2][256];              // x_t transposed [d][b], double buffered
  __shared__ unsigned sdone;                // monotone sentinel counter (16 per step)

  // persistent per-thread weights (VGPRs for all 2048 steps)
  float wreg[3][16];   // w_hh rows (r,z,n) of unit g*32+u, k = ks*16..+15
  float wxreg[3][2];   // w_ih rows, d = ks*2, ks*2+1
  float brz0 = 0.f, brz1 = 0.f, bnx = 0.f, bnh = 0.f;
  #pragma unroll
  for (int i = 0; i < 3; ++i) {
    const int grow = i * Hn + g * UG + u;
    const float4* wp = (const float4*)(w_hh + (size_t)grow * Hn + ks * 16);
    #pragma unroll
    for (int q = 0; q < 4; ++q) {
      const float4 v = wp[q];
      wreg[i][q * 4 + 0] = v.x; wreg[i][q * 4 + 1] = v.y;
      wreg[i][q * 4 + 2] = v.z; wreg[i][q * 4 + 3] = v.w;
    }
    wxreg[i][0] = w_ih[(size_t)grow * Dn + ks * 2 + 0];
    wxreg[i][1] = w_ih[(size_t)grow * Dn + ks * 2 + 1];
    if (i == 0) brz0 = b_ih[grow] + b_hh[grow];
    else if (i == 1) brz1 = b_ih[grow] + b_hh[grow];
    else { bnx = b_ih[grow]; bnh = b_hh[grow]; }
  }

  unsigned long long* const sl0 = xch + (size_t)bg * XW;          // parity 0
  unsigned long long* const sl1 = xch + (size_t)(NBG + bg) * XW;  // parity 1

  for (int idx = tid; idx < 2176; idx += NTH) hTb[0][idx] = 0.f;  // h0 = 0
  if (tid < 256) {
    const int bp = tid >> 6, d = tid & 63;
    xT[0][d * 4 + bp] = x[((size_t)(bg * BPG + bp) * Tn + 0) * Dn + d];
  }
  if (tid == 0) sdone = 0u;
  float hold[BPG] = {0.f, 0.f, 0.f, 0.f};   // own h_{t-1}[u][b] (ks==0 lanes)
  __syncthreads();

  // gather self-skip: ring region [g*128, g*128+128) is written locally via LDS
  const bool skip0 = ((tid >> 7) == g);
  const bool skip1 = (((tid >> 7) + 8) == g);
  const int off0 = tid + 4 * (tid >> 6);          // scatter offset for word tid
  // word tid+1024 -> off0 + 1088

  for (int t = 0; t < Tn; ++t) {
    const int tp = t & 1;
    float* const hT  = hTb[tp];
    float* const hTn = hTb[tp ^ 1];

    // (1) prefetch x_{t+1} (latency hides under discovery)
    float xpre = 0.f;
    if (tid < 256) {
      const int bp = tid >> 6, d = tid & 63;
      const int tn = (t + 1 < Tn) ? (t + 1) : t;
      xpre = x[((size_t)(bg * BPG + bp) * Tn + tn) * Dn + d];
    }

    // (2) gx partials -> accumulator init (merged with gh reduce later)
    // groups: 0=r(gx+gh), 1=z(gx+gh), 2=n x-part, 3=n h-part
    float acc[4][BPG];
    #pragma unroll
    for (int b = 0; b < BPG; ++b) { acc[0][b]=0.f; acc[1][b]=0.f; acc[2][b]=0.f; acc[3][b]=0.f; }
    #pragma unroll
    for (int dd = 0; dd < 2; ++dd) {
      const float4 xb = *(const float4*)&xT[tp][(ks * 2 + dd) * 4];
      #pragma unroll
      for (int i = 0; i < 3; ++i) {
        const float w = wxreg[i][dd];
        const int gi = (i == 2) ? 2 : i;
        acc[gi][0] += w * xb.x; acc[gi][1] += w * xb.y;
        acc[gi][2] += w * xb.z; acc[gi][3] += w * xb.w;
      }
    }

    // (3) discovery + gather of h_{t-1}
    if (t > 0) {
      const unsigned long long* src = tp ? sl0 : sl1;   // slot parity (t-1)&1
      const unsigned long long want = (unsigned long long)t;

      // (3a) 16 pollers watch 16 sentinels (last word of each producer region)
      if (tid < NG) {
        const unsigned long long* sp = src + tid * 128 + 127;
        int guard = 0;
        while ((__hip_atomic_load(sp, __ATOMIC_RELAXED, __HIP_MEMORY_SCOPE_AGENT) >> 32)
               != want) {
          if (++guard > (1 << 17)) break;   // bounded: wrong result beats hang
          if (guard > 8) __builtin_amdgcn_s_sleep(1);
        }
        atomicAdd(&sdone, 1u);
      }
      // (3b) everyone spins on LDS (no fabric traffic)
      {
        int guard = 0;
        while (__hip_atomic_load(&sdone, __ATOMIC_ACQUIRE, __HIP_MEMORY_SCOPE_WORKGROUP)
               < 16u * (unsigned)t) {
          if (++guard > (1 << 20)) break;
          __builtin_amdgcn_s_sleep(1);
        }
      }
      // (3c) single bulk gather, tag-verified (stragglers re-polled; self skipped)
      unsigned long long v0 = want << 32, v1 = want << 32;
      if (!skip0) v0 = __hip_atomic_load(src + tid,        __ATOMIC_RELAXED, __HIP_MEMORY_SCOPE_AGENT);
      if (!skip1) v1 = __hip_atomic_load(src + 1024 + tid, __ATOMIC_RELAXED, __HIP_MEMORY_SCOPE_AGENT);
      int guard = 0;
      while ((((v0 >> 32) != want) | ((v1 >> 32) != want))) {
        if (++guard > (1 << 17)) break;
        if ((v0 >> 32) != want)
          v0 = __hip_atomic_load(src + tid,        __ATOMIC_RELAXED, __HIP_MEMORY_SCOPE_AGENT);
        if ((v1 >> 32) != want)
          v1 = __hip_atomic_load(src + 1024 + tid, __ATOMIC_RELAXED, __HIP_MEMORY_SCOPE_AGENT);
      }
      union { unsigned u32; float f; } c;
      if (!skip0) { c.u32 = (unsigned)v0; hT[off0]        = c.f; }
      if (!skip1) { c.u32 = (unsigned)v1; hT[off0 + 1088] = c.f; }
    }

    // (4) stage x_{t+1}
    if (tid < 256) { const int bp = tid >> 6, d = tid & 63; xT[tp ^ 1][d * 4 + bp] = xpre; }
    __syncthreads();   // the ONLY barrier per step

    // (5) gh partials (weights in VGPRs, h broadcast from LDS)
    {
      const float* hp = hT + ks * 68;
      #pragma unroll
      for (int kk = 0; kk < 16; ++kk) {
        const float4 hb = *(const float4*)(hp + kk * 4);
        const float w0 = wreg[0][kk], w1 = wreg[1][kk], w2 = wreg[2][kk];
        acc[0][0] += w0 * hb.x; acc[0][1] += w0 * hb.y; acc[0][2] += w0 * hb.z; acc[0][3] += w0 * hb.w;
        acc[1][0] += w1 * hb.x; acc[1][1] += w1 * hb.y; acc[1][2] += w1 * hb.z; acc[1][3] += w1 * hb.w;
        acc[3][0] += w2 * hb.x; acc[3][1] += w2 * hb.y; acc[3][2] += w2 * hb.z; acc[3][3] += w2 * hb.w;
      }
    }

    // (6) single merged butterfly reduce over the 32 ks lanes (intra-wave)
    #pragma unroll
    for (int m = 1; m < KS; m <<= 1)
      #pragma unroll
      for (int i = 0; i < 4; ++i)
        #pragma unroll
        for (int b = 0; b < BPG; ++b)
          acc[i][b] += __shfl_xor(acc[i][b], m);

    // (7) combine on ks==0 lanes; publish FIRST; own slice direct to LDS
    if (ks == 0) {
      unsigned long long wpub[BPG];
      float4 hv;
      float* hvp = &hv.x;
      #pragma unroll
      for (int b = 0; b < BPG; ++b) {
        const float r = sigmoidf_(acc[0][b] + brz0);
        const float z = sigmoidf_(acc[1][b] + brz1);
        const float n = tanhf_(acc[2][b] + bnx + r * (acc[3][b] + bnh));
        const float h = (1.f - z) * n + z * hold[b];
        hold[b] = h;
        hvp[b] = h;
        union { float f; unsigned u32; } cu; cu.f = h;
        wpub[b] = ((unsigned long long)(t + 1) << 32) | cu.u32;
      }
      unsigned long long* dst = (tp ? sl1 : sl0) + (g << 7) + (u << 2);
      #pragma unroll
      for (int b = 0; b < BPG; ++b)
        __hip_atomic_store(dst + b, wpub[b], __ATOMIC_RELAXED, __HIP_MEMORY_SCOPE_AGENT);
      // own h straight into next step's hT (skipped by gather)
      const int k = g * UG + u;
      *(float4*)(hTn + k * 4 + ((k >> 4) << 2)) = hv;
      // hs for the FC pass (plain store)
      *(float4*)(hs + ((size_t)t * NBG + bg) * XW + (g << 7) + (u << 2)) = hv;
    }
  }
}

__global__ __launch_bounds__(256) void gru_fc(const float* __restrict__ hs,
    const float* __restrict__ w_fc, const float* __restrict__ b_fc,
    float* __restrict__ out)
{
  __shared__ float wfc[Cn * Hn];  // 20 KB
  const int tid = threadIdx.x;
  for (int i = tid; i < Cn * Hn; i += 256) wfc[i] = w_fc[i];
  __syncthreads();
  const int wave = tid >> 6, lane = tid & 63;
  const int bt = blockIdx.x * 4 + wave;        // = b*Tn + t
  const int b = bt >> 11, t = bt & (Tn - 1);
  const int bg = b >> 2, bp = b & 3;
  const float* src = hs + ((size_t)t * NBG + bg) * XW;
  float acc[Cn];
  #pragma unroll
  for (int c = 0; c < Cn; ++c) acc[c] = 0.f;
  #pragma unroll
  for (int it = 0; it < 8; ++it) {
    const int unit = it * 64 + lane;           // hidden unit 0..511
    const float h = src[((unit >> 5) << 7) + ((unit & 31) << 2) + bp];
    #pragma unroll
    for (int c = 0; c < Cn; ++c) acc[c] += h * wfc[c * Hn + unit];
  }
  #pragma unroll
  for (int c = 0; c < Cn; ++c) {
    #pragma unroll
    for (int m = 1; m < 64; m <<= 1) acc[c] += __shfl_xor(acc[c], m);
  }
  if (lane == 0) {
    #pragma unroll
    for (int c = 0; c < Cn; ++c) out[(size_t)bt * Cn + c] = acc[c] + b_fc[c];
  }
}

// Fallback if workspace too small: one block per batch, no inter-block comms.
__global__ __launch_bounds__(512) void gru_fallback(
    const float* __restrict__ x, const float* __restrict__ w_ih,
    const float* __restrict__ w_hh, const float* __restrict__ b_ih,
    const float* __restrict__ b_hh, const float* __restrict__ w_fc,
    const float* __restrict__ b_fc, float* __restrict__ out)
{
  const int b = blockIdx.x;
  const int tid = threadIdx.x;
  __shared__ float hsh[Hn];
  __shared__ float xsh[Dn];
  hsh[tid] = 0.f;
  __syncthreads();
  for (int t = 0; t < Tn; ++t) {
    if (tid < Dn) xsh[tid] = x[((size_t)b * Tn + t) * Dn + tid];
    __syncthreads();
    const int u = tid;
    float gxr = 0.f, gxz = 0.f, gxn = 0.f;
    for (int d = 0; d < Dn; ++d) {
      const float xv = xsh[d];
      gxr += w_ih[(size_t)u * Dn + d] * xv;
      gxz += w_ih[(size_t)(Hn + u) * Dn + d] * xv;
      gxn += w_ih[(size_t)(2 * Hn + u) * Dn + d] * xv;
    }
    float ghr = 0.f, ghz = 0.f, ghn = 0.f;
    for (int k = 0; k < Hn; ++k) {
      const float hv = hsh[k];
      ghr += w_hh[(size_t)u * Hn + k] * hv;
      ghz += w_hh[(size_t)(Hn + u) * Hn + k] * hv;
      ghn += w_hh[(size_t)(2 * Hn + u) * Hn + k] * hv;
    }
    const float r = sigmoidf_(gxr + b_ih[u] + ghr + b_hh[u]);
    const float z = sigmoidf_(gxz + b_ih[Hn + u] + ghz + b_hh[Hn + u]);
    const float n = tanhf(gxn + b_ih[2 * Hn + u] + r * (ghn + b_hh[2 * Hn + u]));
    const float hold = hsh[u];
    __syncthreads();
    hsh[u] = (1.f - z) * n + z * hold;
    __syncthreads();
    if (tid < 320) {
      const int c = tid >> 5, l = tid & 31;
      float a = 0.f;
      for (int kk = 0; kk < 16; ++kk) {
        const int j = l * 16 + kk;
        a += hsh[j] * w_fc[c * Hn + j];
      }
      a += __shfl_xor(a, 1); a += __shfl_xor(a, 2); a += __shfl_xor(a, 4);
      a += __shfl_xor(a, 8); a += __shfl_xor(a, 16);
      if (l == 0) out[((size_t)b * Tn + t) * Cn + c] = a + b_fc[c];
    }
    __syncthreads();
  }
}

extern "C" void kernel_launch(void* const* d_in, const int* in_sizes, int n_in,
                              void* d_out, int out_size, void* d_ws, size_t ws_size,
                              hipStream_t stream) {
  const float* x    = (const float*)d_in[0];
  const float* w_ih = (const float*)d_in[1];
  const float* w_hh = (const float*)d_in[2];
  const float* b_ih = (const float*)d_in[3];
  const float* b_hh = (const float*)d_in[4];
  const float* w_fc = (const float*)d_in[5];
  const float* b_fc = (const float*)d_in[6];
  float* out = (float*)d_out;

  const size_t hs_bytes  = (size_t)Tn * NBG * XW * sizeof(float);              // 128 MiB
  const size_t xch_bytes = (size_t)2 * NBG * XW * sizeof(unsigned long long);  // 256 KiB

  if (ws_size >= hs_bytes) {
    float* hs = (float*)d_ws;
    // exchange ring lives in d_out (2.6 MB); gru_fc fully overwrites it after.
    unsigned long long* xchg = (unsigned long long*)d_out;
    hipMemsetAsync(xchg, 0, xch_bytes, stream);  // clear tags each launch (graph-safe)
    hipLaunchKernelGGL(gru_main, dim3(NG * NBG), dim3(NTH), 0, stream,
                       x, w_ih, w_hh, b_ih, b_hh, hs, xchg);
    hipLaunchKernelGGL(gru_fc, dim3((Bsz * Tn) / 4), dim3(256), 0, stream,
                       hs, w_fc, b_fc, out);
  } else {
    hipLaunchKernelGGL(gru_fallback, dim3(Bsz), dim3(512), 0, stream,
                       x, w_ih, w_hh, b_ih, b_hh, w_fc, b_fc, out);
  }
}

// Round 8
// 13006.906 us; speedup vs baseline: 1.1633x; 1.1633x over previous
//
#include <hip/hip_runtime.h>
#include <cstdint>
#include <cstddef>

#define Bsz 32
#define Tn  2048
#define Dn  64
#define Hn  512
#define Cn  10
#define NDOM 16   // sync domains (2 batches each)
#define NGB  16   // blocks per domain
#define UG   32   // hidden units per block
#define BPG  2    // batches per domain
#define KS   32   // K-split lanes per unit
#define NTH  1024 // 32 units x 32 ks
#define RW   1024 // ring words per (parity, domain) = 512 units * 2 batches

__device__ __forceinline__ float sigmoidf_(float v) { return 1.f / (1.f + __expf(-v)); }
__device__ __forceinline__ float tanhf_(float v) {
  const float c = fminf(fmaxf(v, -15.f), 15.f);
  const float e = __expf(-2.f * c);
  return (1.f - e) / (1.f + e);
}

// hT layout (BPG=2): ring word j = unit*2 + b -> LDS off = j + ((j>>5)<<1)
//   = k*2 + ((k>>4)<<1) + b ; lane ks reads its 34-float section at hT+ks*34
//   (17-bank stride across lanes -> worst 2-way conflict = free)

__global__ __launch_bounds__(NTH) void gru_main(
    const float* __restrict__ x, const float* __restrict__ w_ih,
    const float* __restrict__ w_hh, const float* __restrict__ b_ih,
    const float* __restrict__ b_hh, float* __restrict__ hs,
    unsigned long long* __restrict__ xch)   // [2][NDOM][RW] tagged ring
{
  const int dom = blockIdx.x & (NDOM - 1);
  const int g   = blockIdx.x >> 4;          // 0..15
  const int tid = threadIdx.x;
  const int ks  = tid & (KS - 1);
  const int u   = tid >> 5;                 // unit within block 0..31

  __shared__ float hTb[2][1088];
  __shared__ float xT[2][128];              // x_t transposed [d][b], double buffered

  // ---- persistent per-thread weights (VGPRs for all 2048 steps) ----
  float wreg[3][16];   // w_hh rows (r,z,n) of unit g*32+u, k = ks*16..+15
  float wxreg[3][2];   // w_ih rows, d = ks*2, ks*2+1
  float brz0 = 0.f, brz1 = 0.f, bnx = 0.f, bnh = 0.f;
  #pragma unroll
  for (int i = 0; i < 3; ++i) {
    const int grow = i * Hn + g * UG + u;
    const float4* wp = (const float4*)(w_hh + (size_t)grow * Hn + ks * 16);
    #pragma unroll
    for (int q = 0; q < 4; ++q) {
      const float4 v = wp[q];
      wreg[i][q * 4 + 0] = v.x; wreg[i][q * 4 + 1] = v.y;
      wreg[i][q * 4 + 2] = v.z; wreg[i][q * 4 + 3] = v.w;
    }
    wxreg[i][0] = w_ih[(size_t)grow * Dn + ks * 2 + 0];
    wxreg[i][1] = w_ih[(size_t)grow * Dn + ks * 2 + 1];
    if (i == 0) brz0 = b_ih[grow] + b_hh[grow];
    else if (i == 1) brz1 = b_ih[grow] + b_hh[grow];
    else { bnx = b_ih[grow]; bnh = b_hh[grow]; }
  }

  unsigned long long* const sl0 = xch + (size_t)dom * RW;          // parity 0
  unsigned long long* const sl1 = xch + (size_t)(NDOM + dom) * RW; // parity 1

  // ---- gather word assignment: ONLY ks!=0 threads poll (publishers never wait) ----
  // rank in [0,960): 31 lanes per unit-group x 31 groups used; skip own 64-word region.
  const int  rank   = u * 31 + ks - 1;                 // valid when ks>0
  const bool dopoll = (ks != 0) && (rank < NGB * 64 - 64);
  const int  wword  = (rank < g * 64) ? rank : rank + 64;
  const int  soff   = wword + ((wword >> 5) << 1);     // LDS scatter offset

  for (int idx = tid; idx < 1088; idx += NTH) hTb[0][idx] = 0.f;  // h0 = 0
  if (tid < 128) {
    const int bp = tid >> 6, d = tid & 63;
    xT[0][d * 2 + bp] = x[((size_t)(dom * BPG + bp) * Tn + 0) * Dn + d];
  }
  float hold[BPG] = {0.f, 0.f};             // own h_{t-1}[u][b] (ks==0 lanes)
  __syncthreads();

  for (int t = 0; t < Tn; ++t) {
    const int tp = t & 1;
    float* const hT  = hTb[tp];
    float* const hTn = hTb[tp ^ 1];
    const float* const xTc = xT[tp];
    float* const xTn       = xT[tp ^ 1];

    // (A1) issue the poll load FIRST (hop-1 hides under gx compute)
    const unsigned long long want = (unsigned long long)t;
    const unsigned long long* src = tp ? sl0 : sl1;    // parity (t-1)&1
    unsigned long long v = 0;
    if (t > 0 && dopoll)
      v = __hip_atomic_load(src + wword, __ATOMIC_RELAXED, __HIP_MEMORY_SCOPE_AGENT);

    // (A2) prefetch x_{t+1}
    float xpre = 0.f;
    if (tid < 128) {
      const int bp = tid >> 6, d = tid & 63;
      const int tn = (t + 1 < Tn) ? (t + 1) : t;
      xpre = x[((size_t)(dom * BPG + bp) * Tn + tn) * Dn + d];
    }

    // (A3) gx partials -> accumulator init (merged with gh reduce later)
    // groups: 0=r, 1=z, 2=n x-part, 3=n h-part
    float acc[4][BPG];
    #pragma unroll
    for (int b = 0; b < BPG; ++b) { acc[0][b]=0.f; acc[1][b]=0.f; acc[2][b]=0.f; acc[3][b]=0.f; }
    #pragma unroll
    for (int dd = 0; dd < 2; ++dd) {
      const float2 xb = *(const float2*)&xTc[(ks * 2 + dd) * 2];
      #pragma unroll
      for (int i = 0; i < 3; ++i) {
        const float w = wxreg[i][dd];
        const int gi = (i == 2) ? 2 : i;
        acc[gi][0] += w * xb.x; acc[gi][1] += w * xb.y;
      }
    }

    // (A4) tag check + tight retry (each retry is one MALL round trip anyway)
    if (t > 0 && dopoll) {
      int gd = 0;
      while ((v >> 32) != want) {
        v = __hip_atomic_load(src + wword, __ATOMIC_RELAXED, __HIP_MEMORY_SCOPE_AGENT);
        if (++gd > (1 << 17)) break;       // bounded: wrong result beats hang
      }
      union { unsigned u32; float f; } c;
      c.u32 = (unsigned)v;
      hT[soff] = c.f;
    }

    // (A5) stage x_{t+1}
    if (tid < 128) { const int bp = tid >> 6, d = tid & 63; xTn[d * 2 + bp] = xpre; }

    // soft barrier: order LDS only; vmem stores stay in flight across it
    asm volatile("s_waitcnt lgkmcnt(0)" ::: "memory");
    __builtin_amdgcn_s_barrier();
    asm volatile("" ::: "memory");
    // free WAW fence: everything outstanding here is >= 1 step old (already done);
    // guarantees prior ring stores retired before this step's same-address publish.
    asm volatile("s_waitcnt vmcnt(0)" ::: "memory");

    // (B1) gh partials (weights in VGPRs, h broadcast from LDS)
    {
      const float* hp = hT + ks * 34;
      #pragma unroll
      for (int kk = 0; kk < 16; ++kk) {
        const float2 hb = *(const float2*)(hp + kk * 2);
        const float w0 = wreg[0][kk], w1 = wreg[1][kk], w2 = wreg[2][kk];
        acc[0][0] += w0 * hb.x; acc[0][1] += w0 * hb.y;
        acc[1][0] += w1 * hb.x; acc[1][1] += w1 * hb.y;
        acc[3][0] += w2 * hb.x; acc[3][1] += w2 * hb.y;
      }
    }

    // (B2) single merged butterfly reduce over the 32 ks lanes (stays in half-wave)
    #pragma unroll
    for (int m = 1; m < KS; m <<= 1)
      #pragma unroll
      for (int i = 0; i < 4; ++i)
        #pragma unroll
        for (int b = 0; b < BPG; ++b)
          acc[i][b] += __shfl_xor(acc[i][b], m);

    // (B3) combine on ks==0 lanes; publish FIRST (fire-and-forget, never waited here)
    if (ks == 0) {
      float h[BPG];
      #pragma unroll
      for (int b = 0; b < BPG; ++b) {
        const float r = sigmoidf_(acc[0][b] + brz0);
        const float z = sigmoidf_(acc[1][b] + brz1);
        const float n = tanhf_(acc[2][b] + bnx + r * (acc[3][b] + bnh));
        h[b] = (1.f - z) * n + z * hold[b];
        hold[b] = h[b];
      }
      union { float f; unsigned u32; } c0, c1;
      c0.f = h[0]; c1.f = h[1];
      if (t + 1 < Tn) {
        const unsigned long long w0 = ((unsigned long long)(t + 1) << 32) | c0.u32;
        const unsigned long long w1 = ((unsigned long long)(t + 1) << 32) | c1.u32;
        unsigned long long* dst = (tp ? sl1 : sl0) + (g << 6) + (u << 1);
        __hip_atomic_store(dst + 0, w0, __ATOMIC_RELAXED, __HIP_MEMORY_SCOPE_AGENT);
        __hip_atomic_store(dst + 1, w1, __ATOMIC_RELAXED, __HIP_MEMORY_SCOPE_AGENT);
      }
      // own slice straight into next step's hT (gather never covers it)
      const int k = g * UG + u;
      const int offn = k * 2 + ((k >> 4) << 1);
      *(float2*)(hTn + offn) = make_float2(h[0], h[1]);
      // hs for the FC pass (background HBM store)
      *(float2*)(hs + ((size_t)t * NDOM + dom) * RW + (g << 6) + (u << 1)) =
          make_float2(h[0], h[1]);
    }
  }
}

__global__ __launch_bounds__(256) void gru_fc(const float* __restrict__ hs,
    const float* __restrict__ w_fc, const float* __restrict__ b_fc,
    float* __restrict__ out)
{
  __shared__ float wfc[Cn * Hn];  // 20 KB
  const int tid = threadIdx.x;
  for (int i = tid; i < Cn * Hn; i += 256) wfc[i] = w_fc[i];
  __syncthreads();
  const int wave = tid >> 6, lane = tid & 63;
  const int bt = blockIdx.x * 4 + wave;        // = b*Tn + t
  const int b = bt >> 11, t = bt & (Tn - 1);
  const int dom = b >> 1, bp = b & 1;
  const float* src = hs + ((size_t)t * NDOM + dom) * RW;
  float acc[Cn];
  #pragma unroll
  for (int c = 0; c < Cn; ++c) acc[c] = 0.f;
  #pragma unroll
  for (int it = 0; it < 8; ++it) {
    const int unit = it * 64 + lane;           // hidden unit 0..511
    const float h = src[unit * 2 + bp];
    #pragma unroll
    for (int c = 0; c < Cn; ++c) acc[c] += h * wfc[c * Hn + unit];
  }
  #pragma unroll
  for (int c = 0; c < Cn; ++c) {
    #pragma unroll
    for (int m = 1; m < 64; m <<= 1) acc[c] += __shfl_xor(acc[c], m);
  }
  if (lane == 0) {
    #pragma unroll
    for (int c = 0; c < Cn; ++c) out[(size_t)bt * Cn + c] = acc[c] + b_fc[c];
  }
}

// Fallback if workspace too small: one block per batch, no inter-block comms.
__global__ __launch_bounds__(512) void gru_fallback(
    const float* __restrict__ x, const float* __restrict__ w_ih,
    const float* __restrict__ w_hh, const float* __restrict__ b_ih,
    const float* __restrict__ b_hh, const float* __restrict__ w_fc,
    const float* __restrict__ b_fc, float* __restrict__ out)
{
  const int b = blockIdx.x;
  const int tid = threadIdx.x;
  __shared__ float hsh[Hn];
  __shared__ float xsh[Dn];
  hsh[tid] = 0.f;
  __syncthreads();
  for (int t = 0; t < Tn; ++t) {
    if (tid < Dn) xsh[tid] = x[((size_t)b * Tn + t) * Dn + tid];
    __syncthreads();
    const int u = tid;
    float gxr = 0.f, gxz = 0.f, gxn = 0.f;
    for (int d = 0; d < Dn; ++d) {
      const float xv = xsh[d];
      gxr += w_ih[(size_t)u * Dn + d] * xv;
      gxz += w_ih[(size_t)(Hn + u) * Dn + d] * xv;
      gxn += w_ih[(size_t)(2 * Hn + u) * Dn + d] * xv;
    }
    float ghr = 0.f, ghz = 0.f, ghn = 0.f;
    for (int k = 0; k < Hn; ++k) {
      const float hv = hsh[k];
      ghr += w_hh[(size_t)u * Hn + k] * hv;
      ghz += w_hh[(size_t)(Hn + u) * Hn + k] * hv;
      ghn += w_hh[(size_t)(2 * Hn + u) * Hn + k] * hv;
    }
    const float r = sigmoidf_(gxr + b_ih[u] + ghr + b_hh[u]);
    const float z = sigmoidf_(gxz + b_ih[Hn + u] + ghz + b_hh[Hn + u]);
    const float n = tanhf(gxn + b_ih[2 * Hn + u] + r * (ghn + b_hh[2 * Hn + u]));
    const float hold = hsh[u];
    __syncthreads();
    hsh[u] = (1.f - z) * n + z * hold;
    __syncthreads();
    if (tid < 320) {
      const int c = tid >> 5, l = tid & 31;
      float a = 0.f;
      for (int kk = 0; kk < 16; ++kk) {
        const int j = l * 16 + kk;
        a += hsh[j] * w_fc[c * Hn + j];
      }
      a += __shfl_xor(a, 1); a += __shfl_xor(a, 2); a += __shfl_xor(a, 4);
      a += __shfl_xor(a, 8); a += __shfl_xor(a, 16);
      if (l == 0) out[((size_t)b * Tn + t) * Cn + c] = a + b_fc[c];
    }
    __syncthreads();
  }
}

extern "C" void kernel_launch(void* const* d_in, const int* in_sizes, int n_in,
                              void* d_out, int out_size, void* d_ws, size_t ws_size,
                              hipStream_t stream) {
  const float* x    = (const float*)d_in[0];
  const float* w_ih = (const float*)d_in[1];
  const float* w_hh = (const float*)d_in[2];
  const float* b_ih = (const float*)d_in[3];
  const float* b_hh = (const float*)d_in[4];
  const float* w_fc = (const float*)d_in[5];
  const float* b_fc = (const float*)d_in[6];
  float* out = (float*)d_out;

  const size_t hs_bytes  = (size_t)Tn * NDOM * RW * sizeof(float);              // 128 MiB
  const size_t xch_bytes = (size_t)2 * NDOM * RW * sizeof(unsigned long long);  // 256 KiB

  if (ws_size >= hs_bytes) {
    float* hs = (float*)d_ws;
    // ring lives in d_out (2.6 MB); gru_fc fully overwrites it after.
    unsigned long long* xchg = (unsigned long long*)d_out;
    hipMemsetAsync(xchg, 0, xch_bytes, stream);  // clear tags each launch (graph-safe)
    hipLaunchKernelGGL(gru_main, dim3(NDOM * NGB), dim3(NTH), 0, stream,
                       x, w_ih, w_hh, b_ih, b_hh, hs, xchg);
    hipLaunchKernelGGL(gru_fc, dim3((Bsz * Tn) / 4), dim3(256), 0, stream,
                       hs, w_fc, b_fc, out);
  } else {
    hipLaunchKernelGGL(gru_fallback, dim3(Bsz), dim3(512), 0, stream,
                       x, w_ih, w_hh, b_ih, b_hh, w_fc, b_fc, out);
  }
}

// Round 9
// 8399.426 us; speedup vs baseline: 1.8014x; 1.5485x over previous
//
#include <hip/hip_runtime.h>
#include <cstdint>
#include <cstddef>

#define Bsz 32
#define Tn  2048
#define Dn  64
#define Hn  512
#define Cn  10
#define NDOM 16   // sync domains (2 batches each)
#define NGB  16   // blocks per domain
#define UG   32   // hidden units per block
#define BPG  2    // batches per domain
#define KS   32   // K-split lanes per unit
#define NTH  1024 // 32 units x 32 ks = 16 waves
#define RW   1024 // ring words per (parity, domain) = 512 units * 2 batches

__device__ __forceinline__ float sigmoidf_(float v) { return 1.f / (1.f + __expf(-v)); }
__device__ __forceinline__ float tanhf_(float v) {
  const float c = fminf(fmaxf(v, -15.f), 15.f);
  const float e = __expf(-2.f * c);
  return (1.f - e) / (1.f + e);
}

// hT layout (BPG=2): ring word j = unit*2 + b -> LDS off = j + ((j>>5)<<1)
//   = k*2 + ((k>>4)<<1) + b ; lane ks reads its 34-float section at hT+ks*34

__global__ __launch_bounds__(NTH) void gru_main(
    const float* __restrict__ x, const float* __restrict__ w_ih,
    const float* __restrict__ w_hh, const float* __restrict__ b_ih,
    const float* __restrict__ b_hh, float* __restrict__ hs,
    unsigned long long* __restrict__ xch)   // [2][NDOM][RW] tagged ring
{
  const int dom  = blockIdx.x & (NDOM - 1);
  const int g    = blockIdx.x >> 4;         // 0..15
  const int tid  = threadIdx.x;
  const int wave = tid >> 6;
  const int lane = tid & 63;
  const int ks   = tid & (KS - 1);
  const int u    = tid >> 5;                // unit within block 0..31

  __shared__ float hTb[2][1088];
  __shared__ float xT[2][128];              // x_t transposed [d][b], double buffered
  __shared__ float hstage[64];              // combine -> publish handoff [u*2+b]
  __shared__ unsigned cnt;                  // monotone handoff counter (32/step)

  // ---- persistent per-thread weights (VGPRs for all 2048 steps) ----
  float wreg[3][16];   // w_hh rows (r,z,n) of unit g*32+u, k = ks*16..+15
  float wxreg[3][2];   // w_ih rows, d = ks*2, ks*2+1
  float brz0 = 0.f, brz1 = 0.f, bnx = 0.f, bnh = 0.f;
  #pragma unroll
  for (int i = 0; i < 3; ++i) {
    const int grow = i * Hn + g * UG + u;
    const float4* wp = (const float4*)(w_hh + (size_t)grow * Hn + ks * 16);
    #pragma unroll
    for (int q = 0; q < 4; ++q) {
      const float4 v = wp[q];
      wreg[i][q * 4 + 0] = v.x; wreg[i][q * 4 + 1] = v.y;
      wreg[i][q * 4 + 2] = v.z; wreg[i][q * 4 + 3] = v.w;
    }
    wxreg[i][0] = w_ih[(size_t)grow * Dn + ks * 2 + 0];
    wxreg[i][1] = w_ih[(size_t)grow * Dn + ks * 2 + 1];
    if (i == 0) brz0 = b_ih[grow] + b_hh[grow];
    else if (i == 1) brz1 = b_ih[grow] + b_hh[grow];
    else { bnx = b_ih[grow]; bnh = b_hh[grow]; }
  }

  unsigned long long* const sl0 = xch + (size_t)dom * RW;          // parity 0
  unsigned long long* const sl1 = xch + (size_t)(NDOM + dom) * RW; // parity 1

  // ---- wave-aligned gather map: waves 0..14 poll the 960 peer words;
  //      wave 15 polls nothing and is the SOLE publisher (its vmem FIFO
  //      holds all global stores; compute waves carry only loads).
  const bool dopoll = (wave < 15);
  int wword = 0, soff = 0;
  if (dopoll) {
    const int idx = wave * 64 + lane;                  // 0..959
    wword = (idx < g * 64) ? idx : idx + 64;           // skip own region
    soff  = wword + ((wword >> 5) << 1);               // LDS scatter offset
  }

  for (int idx = tid; idx < 1088; idx += NTH) hTb[0][idx] = 0.f;   // h0 = 0
  if (tid < 128) {
    const int bp = tid >> 6, d = tid & 63;
    xT[0][d * 2 + bp] = x[((size_t)(dom * BPG + bp) * Tn + 0) * Dn + d];
  }
  if (tid == 0) cnt = 0u;
  float hold[BPG] = {0.f, 0.f};             // own h_{t-1}[u][b] (ks==0 lanes)
  __syncthreads();

  for (int t = 0; t < Tn; ++t) {
    const int tp = t & 1;
    float* const hT  = hTb[tp];
    float* const hTn = hTb[tp ^ 1];
    const float* const xTc = xT[tp];
    float* const xTn       = xT[tp ^ 1];

    // (A1) issue poll load FIRST (hop-1 hides under gx compute)
    const unsigned long long want = (unsigned long long)t;
    const unsigned long long* src = tp ? sl0 : sl1;    // parity (t-1)&1
    unsigned long long v = 0;
    if (t > 0 && dopoll)
      v = __hip_atomic_load(src + wword, __ATOMIC_RELAXED, __HIP_MEMORY_SCOPE_AGENT);

    // (A2) prefetch x_{t+1}
    float xpre = 0.f;
    if (tid < 128) {
      const int bp = tid >> 6, d = tid & 63;
      const int tn = (t + 1 < Tn) ? (t + 1) : t;
      xpre = x[((size_t)(dom * BPG + bp) * Tn + tn) * Dn + d];
    }

    // (A3) gx partials -> accumulator init
    // groups: 0=r, 1=z, 2=n x-part, 3=n h-part
    float acc[4][BPG];
    #pragma unroll
    for (int b = 0; b < BPG; ++b) { acc[0][b]=0.f; acc[1][b]=0.f; acc[2][b]=0.f; acc[3][b]=0.f; }
    #pragma unroll
    for (int dd = 0; dd < 2; ++dd) {
      const float2 xb = *(const float2*)&xTc[(ks * 2 + dd) * 2];
      #pragma unroll
      for (int i = 0; i < 3; ++i) {
        const float w = wxreg[i][dd];
        const int gi = (i == 2) ? 2 : i;
        acc[gi][0] += w * xb.x; acc[gi][1] += w * xb.y;
      }
    }

    // (A4) tag check + tight retry (compute waves have NO outstanding stores,
    //      so the implicit vmcnt waits only on the poll load itself)
    if (t > 0 && dopoll) {
      int gd = 0;
      while ((v >> 32) != want) {
        v = __hip_atomic_load(src + wword, __ATOMIC_RELAXED, __HIP_MEMORY_SCOPE_AGENT);
        if (++gd > (1 << 17)) break;       // bounded: wrong result beats hang
      }
      union { unsigned u32; float f; } c;
      c.u32 = (unsigned)v;
      hT[soff] = c.f;
    }

    // (A5) stage x_{t+1}
    if (tid < 128) { const int bp = tid >> 6, d = tid & 63; xTn[d * 2 + bp] = xpre; }

    // soft barrier: order LDS only; global stores (wave 15's) stay in flight
    asm volatile("s_waitcnt lgkmcnt(0)" ::: "memory");
    __builtin_amdgcn_s_barrier();
    asm volatile("" ::: "memory");

    // (B1) gh partials (weights in VGPRs, h broadcast from LDS)
    {
      const float* hp = hT + ks * 34;
      #pragma unroll
      for (int kk = 0; kk < 16; ++kk) {
        const float2 hb = *(const float2*)(hp + kk * 2);
        const float w0 = wreg[0][kk], w1 = wreg[1][kk], w2 = wreg[2][kk];
        acc[0][0] += w0 * hb.x; acc[0][1] += w0 * hb.y;
        acc[1][0] += w1 * hb.x; acc[1][1] += w1 * hb.y;
        acc[3][0] += w2 * hb.x; acc[3][1] += w2 * hb.y;
      }
    }

    // (B2) merged butterfly reduce over the 32 ks lanes (stays in half-wave)
    #pragma unroll
    for (int m = 1; m < KS; m <<= 1)
      #pragma unroll
      for (int i = 0; i < 4; ++i)
        #pragma unroll
        for (int b = 0; b < BPG; ++b)
          acc[i][b] += __shfl_xor(acc[i][b], m);

    // (B3) combine on ks==0 lanes -> LDS handoff (NO global stores here)
    if (ks == 0) {
      float h[BPG];
      #pragma unroll
      for (int b = 0; b < BPG; ++b) {
        const float r = sigmoidf_(acc[0][b] + brz0);
        const float z = sigmoidf_(acc[1][b] + brz1);
        const float n = tanhf_(acc[2][b] + bnx + r * (acc[3][b] + bnh));
        h[b] = (1.f - z) * n + z * hold[b];
        hold[b] = h[b];
      }
      // own slice straight into next step's hT (gather never covers it)
      const int k = g * UG + u;
      *(float2*)(hTn + k * 2 + ((k >> 4) << 1)) = make_float2(h[0], h[1]);
      // handoff to publisher wave
      *(float2*)(&hstage[u * 2]) = make_float2(h[0], h[1]);
      __hip_atomic_fetch_add(&cnt, 1u, __ATOMIC_RELEASE, __HIP_MEMORY_SCOPE_WORKGROUP);
    }

    // (B4) wave 15: sole publisher. Wait for all 32 units via LDS counter,
    //      then 64 lanes issue the 64 ring words + 64 hs words.
    if (wave == 15) {
      const unsigned target = 32u * (unsigned)(t + 1);
      int gd = 0;
      while (__hip_atomic_load(&cnt, __ATOMIC_ACQUIRE, __HIP_MEMORY_SCOPE_WORKGROUP)
             < target) {
        if (++gd > (1 << 20)) break;
      }
      const float hval = hstage[lane];     // unit lane>>1, batch lane&1
      union { float f; unsigned u32; } cu; cu.f = hval;
      // WAW guard for ring slot reuse: drain own (step-old) stores first
      asm volatile("s_waitcnt vmcnt(0)" ::: "memory");
      if (t + 1 < Tn) {
        const unsigned long long w = ((unsigned long long)(t + 1) << 32) | cu.u32;
        __hip_atomic_store((tp ? sl1 : sl0) + (g << 6) + lane, w,
                           __ATOMIC_RELAXED, __HIP_MEMORY_SCOPE_AGENT);
      }
      hs[((size_t)t * NDOM + dom) * RW + (g << 6) + lane] = hval;
    }
  }
}

__global__ __launch_bounds__(256) void gru_fc(const float* __restrict__ hs,
    const float* __restrict__ w_fc, const float* __restrict__ b_fc,
    float* __restrict__ out)
{
  __shared__ float wfc[Cn * Hn];  // 20 KB
  const int tid = threadIdx.x;
  for (int i = tid; i < Cn * Hn; i += 256) wfc[i] = w_fc[i];
  __syncthreads();
  const int wave = tid >> 6, lane = tid & 63;
  const int bt = blockIdx.x * 4 + wave;        // = b*Tn + t
  const int b = bt >> 11, t = bt & (Tn - 1);
  const int dom = b >> 1, bp = b & 1;
  const float* src = hs + ((size_t)t * NDOM + dom) * RW;
  float acc[Cn];
  #pragma unroll
  for (int c = 0; c < Cn; ++c) acc[c] = 0.f;
  #pragma unroll
  for (int it = 0; it < 8; ++it) {
    const int unit = it * 64 + lane;           // hidden unit 0..511
    const float h = src[unit * 2 + bp];
    #pragma unroll
    for (int c = 0; c < Cn; ++c) acc[c] += h * wfc[c * Hn + unit];
  }
  #pragma unroll
  for (int c = 0; c < Cn; ++c) {
    #pragma unroll
    for (int m = 1; m < 64; m <<= 1) acc[c] += __shfl_xor(acc[c], m);
  }
  if (lane == 0) {
    #pragma unroll
    for (int c = 0; c < Cn; ++c) out[(size_t)bt * Cn + c] = acc[c] + b_fc[c];
  }
}

// Fallback if workspace too small: one block per batch, no inter-block comms.
__global__ __launch_bounds__(512) void gru_fallback(
    const float* __restrict__ x, const float* __restrict__ w_ih,
    const float* __restrict__ w_hh, const float* __restrict__ b_ih,
    const float* __restrict__ b_hh, const float* __restrict__ w_fc,
    const float* __restrict__ b_fc, float* __restrict__ out)
{
  const int b = blockIdx.x;
  const int tid = threadIdx.x;
  __shared__ float hsh[Hn];
  __shared__ float xsh[Dn];
  hsh[tid] = 0.f;
  __syncthreads();
  for (int t = 0; t < Tn; ++t) {
    if (tid < Dn) xsh[tid] = x[((size_t)b * Tn + t) * Dn + tid];
    __syncthreads();
    const int u = tid;
    float gxr = 0.f, gxz = 0.f, gxn = 0.f;
    for (int d = 0; d < Dn; ++d) {
      const float xv = xsh[d];
      gxr += w_ih[(size_t)u * Dn + d] * xv;
      gxz += w_ih[(size_t)(Hn + u) * Dn + d] * xv;
      gxn += w_ih[(size_t)(2 * Hn + u) * Dn + d] * xv;
    }
    float ghr = 0.f, ghz = 0.f, ghn = 0.f;
    for (int k = 0; k < Hn; ++k) {
      const float hv = hsh[k];
      ghr += w_hh[(size_t)u * Hn + k] * hv;
      ghz += w_hh[(size_t)(Hn + u) * Hn + k] * hv;
      ghn += w_hh[(size_t)(2 * Hn + u) * Hn + k] * hv;
    }
    const float r = sigmoidf_(gxr + b_ih[u] + ghr + b_hh[u]);
    const float z = sigmoidf_(gxz + b_ih[Hn + u] + ghz + b_hh[Hn + u]);
    const float n = tanhf(gxn + b_ih[2 * Hn + u] + r * (ghn + b_hh[2 * Hn + u]));
    const float hold = hsh[u];
    __syncthreads();
    hsh[u] = (1.f - z) * n + z * hold;
    __syncthreads();
    if (tid < 320) {
      const int c = tid >> 5, l = tid & 31;
      float a = 0.f;
      for (int kk = 0; kk < 16; ++kk) {
        const int j = l * 16 + kk;
        a += hsh[j] * w_fc[c * Hn + j];
      }
      a += __shfl_xor(a, 1); a += __shfl_xor(a, 2); a += __shfl_xor(a, 4);
      a += __shfl_xor(a, 8); a += __shfl_xor(a, 16);
      if (l == 0) out[((size_t)b * Tn + t) * Cn + c] = a + b_fc[c];
    }
    __syncthreads();
  }
}

extern "C" void kernel_launch(void* const* d_in, const int* in_sizes, int n_in,
                              void* d_out, int out_size, void* d_ws, size_t ws_size,
                              hipStream_t stream) {
  const float* x    = (const float*)d_in[0];
  const float* w_ih = (const float*)d_in[1];
  const float* w_hh = (const float*)d_in[2];
  const float* b_ih = (const float*)d_in[3];
  const float* b_hh = (const float*)d_in[4];
  const float* w_fc = (const float*)d_in[5];
  const float* b_fc = (const float*)d_in[6];
  float* out = (float*)d_out;

  const size_t hs_bytes  = (size_t)Tn * NDOM * RW * sizeof(float);              // 128 MiB
  const size_t xch_bytes = (size_t)2 * NDOM * RW * sizeof(unsigned long long);  // 256 KiB

  if (ws_size >= hs_bytes) {
    float* hs = (float*)d_ws;
    // ring lives in d_out (2.6 MB); gru_fc fully overwrites it after.
    unsigned long long* xchg = (unsigned long long*)d_out;
    hipMemsetAsync(xchg, 0, xch_bytes, stream);  // clear tags each launch (graph-safe)
    hipLaunchKernelGGL(gru_main, dim3(NDOM * NGB), dim3(NTH), 0, stream,
                       x, w_ih, w_hh, b_ih, b_hh, hs, xchg);
    hipLaunchKernelGGL(gru_fc, dim3((Bsz * Tn) / 4), dim3(256), 0, stream,
                       hs, w_fc, b_fc, out);
  } else {
    hipLaunchKernelGGL(gru_fallback, dim3(Bsz), dim3(512), 0, stream,
                       x, w_ih, w_hh, b_ih, b_hh, w_fc, b_fc, out);
  }
}

// Round 10
// 5473.489 us; speedup vs baseline: 2.7644x; 1.5346x over previous
//
#include <hip/hip_runtime.h>
#include <cstdint>
#include <cstddef>

#define Bsz 32
#define Tn  2048
#define Dn  64
#define Hn  512
#define Cn  10
#define NDOM 16   // sync domains (2 batches each)
#define NGB  16   // blocks per domain
#define UG   32   // hidden units per block
#define BPG  2    // batches per domain
#define NTH  1024 // 16 waves: wave owns 32 k; lane = u(5b) | kh(1b)
#define RW   1024 // ring words per (parity, domain) = 512 units * 2 batches
#define PSTR 68   // partial stride (floats) per (b,u) row: 16 waves * 4 grp + pad

__device__ __forceinline__ float sigmoidf_(float v) { return 1.f / (1.f + __expf(-v)); }
__device__ __forceinline__ float tanhf_(float v) {
  const float c = fminf(fmaxf(v, -15.f), 15.f);
  const float e = __expf(-2.f * c);
  return (1.f - e) / (1.f + e);
}

// hT: plain [k*2 + b], 1024 floats (broadcast reads -> no conflicts, no skew)
// part: [b*32+u][PSTR] ; inner = wave*4 + grp  (grp: 0=r 1=z 2=nx 3=nh)

__global__ __launch_bounds__(NTH) void gru_main(
    const float* __restrict__ x, const float* __restrict__ w_ih,
    const float* __restrict__ w_hh, const float* __restrict__ b_ih,
    const float* __restrict__ b_hh, float* __restrict__ hs,
    unsigned long long* __restrict__ xch)   // [2][NDOM][RW] tagged ring
{
  const int dom  = blockIdx.x & (NDOM - 1);
  const int g    = blockIdx.x >> 4;         // 0..15
  const int tid  = threadIdx.x;
  const int wave = tid >> 6;
  const int lane = tid & 63;
  const int u    = tid & 31;                // unit within block
  const int ksec = tid >> 5;                // 0..31: k-range [ksec*16, ksec*16+16)

  __shared__ float hTb[2][1024];
  __shared__ float xT[2][128];              // [d*2 + b], double buffered
  __shared__ float part[64 * PSTR];         // 17 KB partials

  // ---- persistent weights in VGPRs: lane owns k = ksec*16 + [0,16) ----
  float wreg[3][16];   // w_hh rows (r,z,n) of unit g*32+u, cols ksec*16..+15
  float wxreg[3][2];   // w_ih cols d = ksec*2, ksec*2+1
  float brz0 = 0.f, brz1 = 0.f, bnx = 0.f, bnh = 0.f;
  #pragma unroll
  for (int i = 0; i < 3; ++i) {
    const int grow = i * Hn + g * UG + u;
    const float4* wp = (const float4*)(w_hh + (size_t)grow * Hn + ksec * 16);
    #pragma unroll
    for (int q = 0; q < 4; ++q) {
      const float4 v = wp[q];
      wreg[i][q * 4 + 0] = v.x; wreg[i][q * 4 + 1] = v.y;
      wreg[i][q * 4 + 2] = v.z; wreg[i][q * 4 + 3] = v.w;
    }
    wxreg[i][0] = w_ih[(size_t)grow * Dn + ksec * 2 + 0];
    wxreg[i][1] = w_ih[(size_t)grow * Dn + ksec * 2 + 1];
    if (i == 0) brz0 = b_ih[grow] + b_hh[grow];
    else if (i == 1) brz1 = b_ih[grow] + b_hh[grow];
    else { bnx = b_ih[grow]; bnh = b_hh[grow]; }
  }

  unsigned long long* const sl0 = xch + (size_t)dom * RW;          // parity 0
  unsigned long long* const sl1 = xch + (size_t)(NDOM + dom) * RW; // parity 1

  // waves 0..14 poll the 960 peer words; wave 15 = combiner/publisher
  const bool dopoll = (wave < 15);
  int wword = 0;
  if (dopoll) {
    const int idx = wave * 64 + lane;
    wword = (idx < g * 64) ? idx : idx + 64;   // skip own 64-word region
  }
  // w15: own ring word j = g*64 + (lane&31)*2 + (lane>>5)  (unit u=lane&31, b=lane>>5)
  const int ownw = g * 64 + (lane & 31) * 2 + (lane >> 5);

  hTb[0][tid & 1023] = 0.f;                  // h0 = 0 (exactly 1024 threads)
  if (tid < 128) {
    const int bp = tid >> 6, d = tid & 63;
    xT[0][d * 2 + bp] = x[((size_t)(dom * BPG + bp) * Tn + 0) * Dn + d];
  }
  float hold = 0.f;                          // w15 lane's own h (u=lane&31, b=lane>>5)
  __syncthreads();

  for (int t = 0; t < Tn; ++t) {
    const int tp = t & 1;
    float* const hT = hTb[tp];
    unsigned long long* const slot = tp ? sl0 : sl1;   // parity (t-1)&1

    // (A1) consumers: issue poll load FIRST (hop hides under gx)
    const unsigned long long want = (unsigned long long)t;
    unsigned long long v = 0;
    if (t > 0 && dopoll)
      v = __hip_atomic_load(slot + wword, __ATOMIC_RELAXED, __HIP_MEMORY_SCOPE_AGENT);

    // (A2) prefetch x_{t+1}
    float xpre = 0.f;
    if (tid < 128) {
      const int bp = tid >> 6, d = tid & 63;
      const int tn = (t + 1 < Tn) ? (t + 1) : t;
      xpre = x[((size_t)(dom * BPG + bp) * Tn + tn) * Dn + d];
    }

    // (A3) gx partials (all 16 waves; lane owns d = ksec*2, ksec*2+1)
    // acc groups: 0=r, 1=z, 2=n x-part, 3=n h-part
    float acc[4][2];
    #pragma unroll
    for (int i = 0; i < 4; ++i) { acc[i][0] = 0.f; acc[i][1] = 0.f; }
    #pragma unroll
    for (int dd = 0; dd < 2; ++dd) {
      const float2 xb = *(const float2*)&xT[tp][(ksec * 2 + dd) * 2]; // broadcast
      #pragma unroll
      for (int i = 0; i < 3; ++i) {
        const float w = wxreg[i][dd];
        const int gi = (i == 2) ? 2 : i;
        acc[gi][0] += w * xb.x; acc[gi][1] += w * xb.y;
      }
    }

    if (dopoll) {
      // (A4a) tag check + tight retry, then scatter into hT
      if (t > 0) {
        int gd = 0;
        while ((v >> 32) != want) {
          v = __hip_atomic_load(slot + wword, __ATOMIC_RELAXED, __HIP_MEMORY_SCOPE_AGENT);
          if (++gd > (1 << 17)) break;     // bounded: wrong result beats hang
        }
        union { unsigned u32; float f; } c;
        c.u32 = (unsigned)v;
        hT[wword] = c.f;
      }
    } else if (t > 0) {
      // (A4b) wave 15: sum 16 partials -> combine -> publish h_{t-1}
      const float4* pp = (const float4*)&part[lane * PSTR];
      float4 s = pp[0];
      #pragma unroll
      for (int w = 1; w < 16; ++w) {
        const float4 pv = pp[w];
        s.x += pv.x; s.y += pv.y; s.z += pv.z; s.w += pv.w;
      }
      const float r = sigmoidf_(s.x + brz0);
      const float z = sigmoidf_(s.y + brz1);
      const float n = tanhf_(s.z + bnx + r * (s.w + bnh));
      const float h = (1.f - z) * n + z * hold;
      hold = h;
      hT[ownw] = h;                          // own slice for this step's gh
      union { float f; unsigned u32; } cu; cu.f = h;
      // WAW guard: drain own (2-step-old) ring stores before slot reuse
      asm volatile("s_waitcnt vmcnt(0)" ::: "memory");
      const unsigned long long w64 = (want << 32) | cu.u32;
      __hip_atomic_store(slot + ownw, w64, __ATOMIC_RELAXED, __HIP_MEMORY_SCOPE_AGENT);
      hs[((size_t)(t - 1) * NDOM + dom) * RW + ownw] = h;
    }

    // (A5) stage x_{t+1}
    if (tid < 128) { const int bp = tid >> 6, d = tid & 63; xT[tp ^ 1][d * 2 + bp] = xpre; }

    // BARRIER A (soft: LDS-order only; global stores stay in flight)
    asm volatile("s_waitcnt lgkmcnt(0)" ::: "memory");
    __builtin_amdgcn_s_barrier();
    asm volatile("" ::: "memory");

    // (B1) gh partials: broadcast float4 reads (h[k][0],h[k][1],h[k+1][0],h[k+1][1])
    {
      const float* hp = hT + ksec * 32;
      #pragma unroll
      for (int k2 = 0; k2 < 8; ++k2) {
        const float4 hv = *(const float4*)(hp + k2 * 4);
        const float a0 = wreg[0][k2 * 2], a1 = wreg[0][k2 * 2 + 1];
        const float b0 = wreg[1][k2 * 2], b1 = wreg[1][k2 * 2 + 1];
        const float c0 = wreg[2][k2 * 2], c1 = wreg[2][k2 * 2 + 1];
        acc[0][0] += a0 * hv.x; acc[0][1] += a0 * hv.y;
        acc[0][0] += a1 * hv.z; acc[0][1] += a1 * hv.w;
        acc[1][0] += b0 * hv.x; acc[1][1] += b0 * hv.y;
        acc[1][0] += b1 * hv.z; acc[1][1] += b1 * hv.w;
        acc[3][0] += c0 * hv.x; acc[3][1] += c0 * hv.y;
        acc[3][0] += c1 * hv.z; acc[3][1] += c1 * hv.w;
      }
    }

    // (B2) single cross-half reduce (k-halves live in lane and lane^32)
    #pragma unroll
    for (int i = 0; i < 4; ++i) {
      acc[i][0] += __shfl_xor(acc[i][0], 32);
      acc[i][1] += __shfl_xor(acc[i][1], 32);
    }

    // (B3) write wave partials (deterministic; fully overwritten each step)
    if (lane < 32) {
      float4 p0, p1;
      p0.x = acc[0][0]; p0.y = acc[1][0]; p0.z = acc[2][0]; p0.w = acc[3][0];
      p1.x = acc[0][1]; p1.y = acc[1][1]; p1.z = acc[2][1]; p1.w = acc[3][1];
      *(float4*)&part[u * PSTR + wave * 4]        = p0;   // b = 0
      *(float4*)&part[(32 + u) * PSTR + wave * 4] = p1;   // b = 1
    }

    // BARRIER B (soft)
    asm volatile("s_waitcnt lgkmcnt(0)" ::: "memory");
    __builtin_amdgcn_s_barrier();
    asm volatile("" ::: "memory");
  }

  // epilogue: combine + store h_{Tn-1} (no ring publish needed)
  if (wave == 15) {
    const float4* pp = (const float4*)&part[lane * PSTR];
    float4 s = pp[0];
    #pragma unroll
    for (int w = 1; w < 16; ++w) {
      const float4 pv = pp[w];
      s.x += pv.x; s.y += pv.y; s.z += pv.z; s.w += pv.w;
    }
    const float r = sigmoidf_(s.x + brz0);
    const float z = sigmoidf_(s.y + brz1);
    const float n = tanhf_(s.z + bnx + r * (s.w + bnh));
    const float h = (1.f - z) * n + z * hold;
    hs[((size_t)(Tn - 1) * NDOM + dom) * RW + ownw] = h;
  }
}

__global__ __launch_bounds__(256) void gru_fc(const float* __restrict__ hs,
    const float* __restrict__ w_fc, const float* __restrict__ b_fc,
    float* __restrict__ out)
{
  __shared__ float wfc[Cn * Hn];  // 20 KB
  const int tid = threadIdx.x;
  for (int i = tid; i < Cn * Hn; i += 256) wfc[i] = w_fc[i];
  __syncthreads();
  const int wave = tid >> 6, lane = tid & 63;
  const int bt = blockIdx.x * 4 + wave;        // = b*Tn + t
  const int b = bt >> 11, t = bt & (Tn - 1);
  const int dom = b >> 1, bp = b & 1;
  const float* src = hs + ((size_t)t * NDOM + dom) * RW;
  float acc[Cn];
  #pragma unroll
  for (int c = 0; c < Cn; ++c) acc[c] = 0.f;
  #pragma unroll
  for (int it = 0; it < 8; ++it) {
    const int unit = it * 64 + lane;           // hidden unit 0..511
    const float h = src[unit * 2 + bp];
    #pragma unroll
    for (int c = 0; c < Cn; ++c) acc[c] += h * wfc[c * Hn + unit];
  }
  #pragma unroll
  for (int c = 0; c < Cn; ++c) {
    #pragma unroll
    for (int m = 1; m < 64; m <<= 1) acc[c] += __shfl_xor(acc[c], m);
  }
  if (lane == 0) {
    #pragma unroll
    for (int c = 0; c < Cn; ++c) out[(size_t)bt * Cn + c] = acc[c] + b_fc[c];
  }
}

// Fallback if workspace too small: one block per batch, no inter-block comms.
__global__ __launch_bounds__(512) void gru_fallback(
    const float* __restrict__ x, const float* __restrict__ w_ih,
    const float* __restrict__ w_hh, const float* __restrict__ b_ih,
    const float* __restrict__ b_hh, const float* __restrict__ w_fc,
    const float* __restrict__ b_fc, float* __restrict__ out)
{
  const int b = blockIdx.x;
  const int tid = threadIdx.x;
  __shared__ float hsh[Hn];
  __shared__ float xsh[Dn];
  hsh[tid] = 0.f;
  __syncthreads();
  for (int t = 0; t < Tn; ++t) {
    if (tid < Dn) xsh[tid] = x[((size_t)b * Tn + t) * Dn + tid];
    __syncthreads();
    const int u = tid;
    float gxr = 0.f, gxz = 0.f, gxn = 0.f;
    for (int d = 0; d < Dn; ++d) {
      const float xv = xsh[d];
      gxr += w_ih[(size_t)u * Dn + d] * xv;
      gxz += w_ih[(size_t)(Hn + u) * Dn + d] * xv;
      gxn += w_ih[(size_t)(2 * Hn + u) * Dn + d] * xv;
    }
    float ghr = 0.f, ghz = 0.f, ghn = 0.f;
    for (int k = 0; k < Hn; ++k) {
      const float hv = hsh[k];
      ghr += w_hh[(size_t)u * Hn + k] * hv;
      ghz += w_hh[(size_t)(Hn + u) * Hn + k] * hv;
      ghn += w_hh[(size_t)(2 * Hn + u) * Hn + k] * hv;
    }
    const float r = sigmoidf_(gxr + b_ih[u] + ghr + b_hh[u]);
    const float z = sigmoidf_(gxz + b_ih[Hn + u] + ghz + b_hh[Hn + u]);
    const float n = tanhf(gxn + b_ih[2 * Hn + u] + r * (ghn + b_hh[2 * Hn + u]));
    const float hold = hsh[u];
    __syncthreads();
    hsh[u] = (1.f - z) * n + z * hold;
    __syncthreads();
    if (tid < 320) {
      const int c = tid >> 5, l = tid & 31;
      float a = 0.f;
      for (int kk = 0; kk < 16; ++kk) {
        const int j = l * 16 + kk;
        a += hsh[j] * w_fc[c * Hn + j];
      }
      a += __shfl_xor(a, 1); a += __shfl_xor(a, 2); a += __shfl_xor(a, 4);
      a += __shfl_xor(a, 8); a += __shfl_xor(a, 16);
      if (l == 0) out[((size_t)b * Tn + t) * Cn + c] = a + b_fc[c];
    }
    __syncthreads();
  }
}

extern "C" void kernel_launch(void* const* d_in, const int* in_sizes, int n_in,
                              void* d_out, int out_size, void* d_ws, size_t ws_size,
                              hipStream_t stream) {
  const float* x    = (const float*)d_in[0];
  const float* w_ih = (const float*)d_in[1];
  const float* w_hh = (const float*)d_in[2];
  const float* b_ih = (const float*)d_in[3];
  const float* b_hh = (const float*)d_in[4];
  const float* w_fc = (const float*)d_in[5];
  const float* b_fc = (const float*)d_in[6];
  float* out = (float*)d_out;

  const size_t hs_bytes  = (size_t)Tn * NDOM * RW * sizeof(float);              // 128 MiB
  const size_t xch_bytes = (size_t)2 * NDOM * RW * sizeof(unsigned long long);  // 256 KiB

  if (ws_size >= hs_bytes) {
    float* hs = (float*)d_ws;
    // ring lives in d_out (2.6 MB); gru_fc fully overwrites it after.
    unsigned long long* xchg = (unsigned long long*)d_out;
    hipMemsetAsync(xchg, 0, xch_bytes, stream);  // clear tags each launch (graph-safe)
    hipLaunchKernelGGL(gru_main, dim3(NDOM * NGB), dim3(NTH), 0, stream,
                       x, w_ih, w_hh, b_ih, b_hh, hs, xchg);
    hipLaunchKernelGGL(gru_fc, dim3((Bsz * Tn) / 4), dim3(256), 0, stream,
                       hs, w_fc, b_fc, out);
  } else {
    hipLaunchKernelGGL(gru_fallback, dim3(Bsz), dim3(512), 0, stream,
                       x, w_ih, w_hh, b_ih, b_hh, w_fc, b_fc, out);
  }
}